// Round 5
// baseline (38.765 us; speedup 1.0000x reference)
//
#include <hip/hip_runtime.h>
#include <stdint.h>
#include <math.h>

#define WAVE 64
#define TOPK 16

// Monotone bijection fp32 -> uint32 (order-preserving).
__device__ __forceinline__ uint32_t f2s(float f) {
    uint32_t u = __float_as_uint(f);
    return u ^ (uint32_t)(((int32_t)u >> 31) | 0x80000000u);
}
__device__ __forceinline__ float s2f(uint32_t s) {
    uint32_t u = (s & 0x80000000u) ? (s ^ 0x80000000u) : ~s;
    return __uint_as_float(u);
}
__device__ __forceinline__ uint32_t umax32(uint32_t a, uint32_t b) { return a > b ? a : b; }
__device__ __forceinline__ uint32_t umin32(uint32_t a, uint32_t b) { return a < b ? a : b; }

// compare-exchange, descending (a keeps max)
__device__ __forceinline__ void ce(uint32_t& a, uint32_t& b) {
    uint32_t hi = umax32(a, b), lo = umin32(a, b);
    a = hi; b = lo;
}

// Clean a bitonic sequence a[0..N-1] into descending order.
template <int N>
__device__ __forceinline__ void clean_desc(uint32_t* a) {
#pragma unroll
    for (int stride = N / 2; stride >= 1; stride >>= 1) {
#pragma unroll
        for (int i = 0; i < N; ++i) {
            if ((i & stride) == 0) ce(a[i], a[i | stride]);
        }
    }
}

// Full bitonic sort, descending.
template <int N>
__device__ __forceinline__ void sort_desc(uint32_t* a) {
#pragma unroll
    for (int size = 2; size <= N; size <<= 1) {
#pragma unroll
        for (int stride = size >> 1; stride >= 1; stride >>= 1) {
#pragma unroll
            for (int i = 0; i < N; ++i) {
                const int j = i ^ stride;
                if (j > i) {
                    if ((i & size) == 0) ce(a[i], a[j]);
                    else                 ce(a[j], a[i]);
                }
            }
        }
    }
}

// Cross-lane fetch primitives.
template <int CTRL>
__device__ __forceinline__ uint32_t dpp_mov(uint32_t x) {
    return (uint32_t)__builtin_amdgcn_update_dpp((int)x, (int)x, CTRL, 0xF, 0xF, false);
}
__device__ __forceinline__ uint32_t swz16(uint32_t x) {
    return (uint32_t)__builtin_amdgcn_ds_swizzle((int)x, 0x401F);  // lane ^ 16
}
__device__ __forceinline__ uint32_t bperm32(int xaddr, uint32_t x) {
    return (uint32_t)__builtin_amdgcn_ds_bpermute(xaddr, (int)x);  // lane ^ 32
}

// top-16 of two descending 16-lists (half-cleaner + clean).
__device__ __forceinline__ void merge_top16(uint32_t* a, const uint32_t* r) {
#pragma unroll
    for (int i = 0; i < 16; ++i) a[i] = umax32(a[i], r[15 - i]);
    clean_desc<16>(a);
}

// full merge of two descending L-lists -> descending 2L-list in a.
template <int L>
__device__ __forceinline__ void merge_grow(uint32_t* a, const uint32_t* r) {
#pragma unroll
    for (int i = 0; i < L; ++i) a[L + i] = r[L - 1 - i];
    clean_desc<2 * L>(a);
}

// global position from (local slot j, lane) -- matches the load layout
template <int VPL>
__device__ __forceinline__ uint32_t gpos(int j, int lane) {
    if constexpr (VPL == 1) return (uint32_t)lane;
    else return (uint32_t)((j >> 2) * (WAVE * 4) + lane * 4 + (j & 3));
}

// One wave per output row. qkey = (f2s(v) & ~(P-1)) | global_pos -> unique
// total order matching stable argsort[-k:]. Merge-tournament selection:
// per-lane sort + 6 symmetric merge steps; every lane ends with the global
// top-16 descending. Boundary ambiguity -> exact lexicographic fallback.
template <int P>
__global__ void topk_wm_kernel(const float* __restrict__ conn,
                               const int* __restrict__ rowsel,
                               const float* __restrict__ parent,
                               float* __restrict__ out,
                               int n) {
    constexpr int VPL = P / WAVE;
    constexpr uint32_t IMASK = (uint32_t)(P - 1);
    const int lane = threadIdx.x & (WAVE - 1);
    const int row = blockIdx.x * (blockDim.x >> 6) + (threadIdx.x >> 6);
    if (row >= n) return;

    const long src_row = rowsel ? (long)rowsel[row] : (long)row;
    const float* __restrict__ crow = conn + src_row * (long)P;

    uint32_t a[16];   // merge lists (grow to 16)
    uint32_t b[VPL];  // retained copy of packed keys (for ambiguity count)

    if constexpr (VPL == 1) {
        b[0] = (f2s(crow[lane]) & ~IMASK) | (uint32_t)lane;
        a[0] = b[0];
    } else {
#pragma unroll
        for (int c = 0; c < VPL / 4; ++c) {
            float4 f4 = *reinterpret_cast<const float4*>(crow + c * (WAVE * 4) + lane * 4);
            const uint32_t base = (uint32_t)(c * (WAVE * 4) + lane * 4);
            b[c * 4 + 0] = (f2s(f4.x) & ~IMASK) | (base + 0u);
            b[c * 4 + 1] = (f2s(f4.y) & ~IMASK) | (base + 1u);
            b[c * 4 + 2] = (f2s(f4.z) & ~IMASK) | (base + 2u);
            b[c * 4 + 3] = (f2s(f4.w) & ~IMASK) | (base + 3u);
        }
#pragma unroll
        for (int j = 0; j < VPL; ++j) a[j] = b[j];
        sort_desc<VPL>(a);
    }

    const int xaddr = (lane ^ 32) << 2;
    uint32_t r[16];

    // 6 merge directions covering all 64 lanes:
    //   DS steps (xor32, xor16) done while lists are SHORT for VPL<16;
    //   rot1/2/4/8 are DPP row_ror (pure VALU) within rows of 16.
    if constexpr (VPL == 1) {
        r[0] = bperm32(xaddr, a[0]);
        a[1] = r[0]; clean_desc<2>(a);                          // xor32: 1->2
        r[0] = swz16(a[0]); r[1] = swz16(a[1]);
        merge_grow<2>(a, r);                                    // xor16: 2->4
#pragma unroll
        for (int i = 0; i < 4; ++i) r[i] = dpp_mov<0x121>(a[i]);
        merge_grow<4>(a, r);                                    // rot1: 4->8
#pragma unroll
        for (int i = 0; i < 8; ++i) r[i] = dpp_mov<0x122>(a[i]);
        merge_grow<8>(a, r);                                    // rot2: 8->16
#pragma unroll
        for (int i = 0; i < 16; ++i) r[i] = dpp_mov<0x124>(a[i]);
        merge_top16(a, r);                                      // rot4
#pragma unroll
        for (int i = 0; i < 16; ++i) r[i] = dpp_mov<0x128>(a[i]);
        merge_top16(a, r);                                      // rot8
    } else if constexpr (VPL == 4) {
#pragma unroll
        for (int i = 0; i < 4; ++i) r[i] = bperm32(xaddr, a[i]);
        merge_grow<4>(a, r);                                    // xor32: 4->8
#pragma unroll
        for (int i = 0; i < 8; ++i) r[i] = swz16(a[i]);
        merge_grow<8>(a, r);                                    // xor16: 8->16
#pragma unroll
        for (int i = 0; i < 16; ++i) r[i] = dpp_mov<0x121>(a[i]);
        merge_top16(a, r);
#pragma unroll
        for (int i = 0; i < 16; ++i) r[i] = dpp_mov<0x122>(a[i]);
        merge_top16(a, r);
#pragma unroll
        for (int i = 0; i < 16; ++i) r[i] = dpp_mov<0x124>(a[i]);
        merge_top16(a, r);
#pragma unroll
        for (int i = 0; i < 16; ++i) r[i] = dpp_mov<0x128>(a[i]);
        merge_top16(a, r);
    } else {  // VPL == 16
#pragma unroll
        for (int i = 0; i < 16; ++i) r[i] = dpp_mov<0x121>(a[i]);
        merge_top16(a, r);
#pragma unroll
        for (int i = 0; i < 16; ++i) r[i] = dpp_mov<0x122>(a[i]);
        merge_top16(a, r);
#pragma unroll
        for (int i = 0; i < 16; ++i) r[i] = dpp_mov<0x124>(a[i]);
        merge_top16(a, r);
#pragma unroll
        for (int i = 0; i < 16; ++i) r[i] = dpp_mov<0x128>(a[i]);
        merge_top16(a, r);
#pragma unroll
        for (int i = 0; i < 16; ++i) r[i] = swz16(a[i]);
        merge_top16(a, r);
#pragma unroll
        for (int i = 0; i < 16; ++i) r[i] = bperm32(xaddr, a[i]);
        merge_top16(a, r);
    }
    // a[0..15] = global top-16 keys, descending, identical on all lanes.

    // Ambiguity: exact set can differ from quantized set only if some element
    // with the 16th key's prefix was NOT selected. Count row-wide vs selected.
    const uint32_t q16 = a[15] & ~IMASK;
    int cl = 0;
#pragma unroll
    for (int j = 0; j < VPL; ++j) cl += ((b[j] & ~IMASK) == q16) ? 1 : 0;
    // wave-sum via the same move network (rot adds + xor16 + xor32)
    cl += (int)dpp_mov<0x121>((uint32_t)cl);
    cl += (int)dpp_mov<0x122>((uint32_t)cl);
    cl += (int)dpp_mov<0x124>((uint32_t)cl);
    cl += (int)dpp_mov<0x128>((uint32_t)cl);
    cl += (int)swz16((uint32_t)cl);
    cl += (int)bperm32(xaddr, (uint32_t)cl);
    int cs = 0;
#pragma unroll
    for (int t = 0; t < TOPK; ++t) cs += ((a[t] & ~IMASK) == q16) ? 1 : 0;

    if (cl != cs) {
        // EXACT fallback (rare): lexicographic (value, index) iterative extract.
        uint32_t v[VPL];
        if constexpr (VPL == 1) {
            v[0] = f2s(crow[lane]);
        } else {
#pragma unroll
            for (int c = 0; c < VPL / 4; ++c) {
                float4 f4 = *reinterpret_cast<const float4*>(crow + c * (WAVE * 4) + lane * 4);
                v[c * 4 + 0] = f2s(f4.x);
                v[c * 4 + 1] = f2s(f4.y);
                v[c * 4 + 2] = f2s(f4.z);
                v[c * 4 + 3] = f2s(f4.w);
            }
        }
#pragma unroll
        for (int t = 0; t < TOPK; ++t) {
            uint32_t m = v[0];
            int li = 0;
#pragma unroll
            for (int j = 1; j < VPL; ++j) {
                bool c = v[j] >= m;
                m = c ? v[j] : m;
                li = c ? j : li;
            }
            uint32_t gi = gpos<VPL>(li, lane);
            const uint32_t mygi = gi;
            uint32_t mm = m;
#pragma unroll
            for (int off = 32; off > 0; off >>= 1) {
                uint32_t om = (uint32_t)__shfl_xor((int)mm, off);
                uint32_t og = (uint32_t)__shfl_xor((int)gi, off);
                bool c = (om > mm) || (om == mm && og > gi);
                mm = c ? om : mm;
                gi = c ? og : gi;
            }
            a[t] = gi;  // uniform; prefix bits zero, masked at use
            const bool won = (mygi == gi) && (m == mm);
#pragma unroll
            for (int j = 0; j < VPL; ++j) {
                if (won && j == li) v[j] = 0u;
            }
        }
    }

    // Epilogue: exact values re-read (cache-hot), softmax, weighted gather.
    float vsel[TOPK];
#pragma unroll
    for (int t = 0; t < TOPK; ++t) vsel[t] = crow[a[t] & IMASK];
    const float v0 = vsel[0];  // max (a[] descending / fallback extract order)
    float ssum = 0.f, acc = 0.f;
#pragma unroll
    for (int t = 0; t < TOPK; ++t) {
        const float w = __expf(vsel[t] - v0);
        ssum += w;
        acc = fmaf(w, parent[(a[t] & IMASK) * 64u + (uint32_t)lane], acc);
    }
    out[(long)row * 64 + lane] = acc / ssum;
}

extern "C" void kernel_launch(void* const* d_in, const int* in_sizes, int n_in,
                              void* d_out, int out_size, void* d_ws, size_t ws_size,
                              hipStream_t stream) {
    const int* ids = (const int*)d_in[0];          // [8192] int32
    const float* conn1 = (const float*)d_in[1];    // [200000, 1024]
    const float* conn2 = (const float*)d_in[2];    // [1024, 256]
    const float* conn3 = (const float*)d_in[3];    // [256, 64]
    const float* root = (const float*)d_in[4];     // [64, 64]
    float* out = (float*)d_out;                    // [8192, 64]

    const int batch = in_sizes[0];                 // 8192
    const int n1 = 1024, n2 = 256;

    float* e2 = (float*)d_ws;                      // [256, 64]
    float* e1 = e2 + (size_t)n2 * 64;              // [1024, 64]

    dim3 blk(256);  // 4 waves/block, one wave per row

    topk_wm_kernel<64><<<dim3(n2 / 4), blk, 0, stream>>>(conn3, nullptr, root, e2, n2);
    topk_wm_kernel<256><<<dim3(n1 / 4), blk, 0, stream>>>(conn2, nullptr, e2, e1, n1);
    topk_wm_kernel<1024><<<dim3(batch / 4), blk, 0, stream>>>(conn1, ids, e1, out, batch);
}